// Round 1
// baseline (1298.586 us; speedup 1.0000x reference)
//
#include <hip/hip_runtime.h>
#include <math.h>

#define BATCH   8
#define HH      160
#define WW      576
#define CCH     96
#define NDISP   65        // MAX_DISP+1
#define ENT_THR 0.65f
#define EPSF    1e-8f
// ROI bounds replicated from reference float arithmetic:
// floor(0.3*576)=172, ceil(0.7*576)-1=403, floor((2/3)*160)=106, ceil(1.0*160)-1=159
#define ROI_U0  172
#define ROI_U1  403
#define ROI_V0  106
#define ROI_V1  159

// -EPS*ln(EPS) for the p=max(prob,EPS) clamp terms
#define NEG_EPS_LN_EPS 1.8420680743952367e-7f

__global__ __launch_bounds__(WW) void roi_ent_sl1_row_kernel(
    const float* __restrict__ FqL,
    const float* __restrict__ FqR,
    const float* __restrict__ sdisp,
    float* __restrict__ acc /* [BATCH][2]: sumL, cnt */)
{
    const int row  = blockIdx.x;        // 0..BATCH*HH-1
    const int b    = row / HH;
    const int h    = row - b * HH;
    const int w    = threadIdx.x;       // 0..575
    const int lane = w & 63;
    const int wave = w >> 6;            // 0..8

    __shared__ float Rst[WW * 4];       // R chunk staging [w][4c], contiguous b128
    __shared__ float Pbuf[WW + 1];      // prefix-sum buffer
    __shared__ int   wscanA[16];        // per-wave max for prev_valid
    __shared__ int   wscanB[16];        // per-wave min for next_valid
    __shared__ float wsum[16];          // per-wave partial sums (scan)
    __shared__ float wredL[16];
    __shared__ float wredC[16];

    const size_t rowOff = (size_t)(b * HH + h) * (size_t)WW * CCH;
    const float* Lp = FqL + rowOff + (size_t)w * CCH;
    const float* Rp = FqR + rowOff + (size_t)w * CCH;

    // ---------------- Phase 1: cost volume column in registers ----------------
    float cost[NDISP];
    #pragma unroll
    for (int d = 0; d < NDISP; ++d) cost[d] = (d <= w) ? 0.f : -INFINITY;

    for (int cc = 0; cc < CCH; cc += 4) {
        __syncthreads();                       // protect Rst from prev-iter readers
        float4 rv = *(const float4*)(Rp + cc);
        float4 lv = *(const float4*)(Lp + cc);
        *(float4*)(&Rst[w * 4]) = rv;
        __syncthreads();
        #pragma unroll
        for (int d = 0; d < NDISP; ++d) {
            int idx = w - d;
            int ci  = idx < 0 ? 0 : idx;       // clamp (masked lanes broadcast addr 0)
            float4 r = *(const float4*)(&Rst[ci * 4]);
            float dv = lv.x * r.x + lv.y * r.y + lv.z * r.z + lv.w * r.w;
            cost[d] += (idx >= 0) ? dv : 0.f;  // -inf + 0 stays -inf for d>w
        }
    }

    // ---------------- Phase 2: entropy per pixel ----------------
    float m = -INFINITY;
    #pragma unroll
    for (int d = 0; d < NDISP; ++d) m = (d <= w) ? fmaxf(m, cost[d]) : m;

    float S = 0.f;
    #pragma unroll
    for (int d = 0; d < NDISP; ++d) {
        float e = __expf((cost[d] - m) * 10.0f);   // 1/T = 10
        S += (d <= w) ? e : 0.f;
    }
    float lnS = __logf(S);
    float ent = 0.f;
    #pragma unroll
    for (int d = 0; d < NDISP; ++d) {
        float l = (cost[d] - m) * 10.0f;
        float e = __expf(l);
        float p = e / S;
        // -p*ln p = p*(lnS - l) for unclamped; clamped entries give -EPS*ln(EPS)
        float t = ((d <= w) && (p > EPSF)) ? (p * (lnS - l)) : NEG_EPS_LN_EPS;
        ent += t;
    }
    int Deff = ((w < 64) ? w : 64) + 1;
    ent = (Deff > 1) ? (ent / (__logf((float)Deff) + EPSF)) : 0.f;
    ent = fminf(fmaxf(ent, 0.f), 1.f);
    const bool valid = (ent <= ENT_THR);

    // ---------------- Phase 3: run extents (block-wide scans) ----------------
    int x = valid ? w : -1;                 // forward inclusive max scan
    #pragma unroll
    for (int off = 1; off < 64; off <<= 1) {
        int y = __shfl_up(x, off, 64);
        x = (lane >= off) ? (x > y ? x : y) : x;
    }
    int x2 = valid ? w : WW;                // reverse inclusive min scan
    #pragma unroll
    for (int off = 1; off < 64; off <<= 1) {
        int y = __shfl_down(x2, off, 64);
        x2 = (lane < 64 - off) ? (x2 < y ? x2 : y) : x2;
    }
    if (lane == 63) wscanA[wave] = x;
    if (lane == 0)  wscanB[wave] = x2;
    __syncthreads();
    int prev_valid = x;
    for (int i = 0; i < wave; ++i) { int v = wscanA[i]; prev_valid = prev_valid > v ? prev_valid : v; }
    int next_valid = x2;
    for (int i = wave + 1; i < 9; ++i) { int v = wscanB[i]; next_valid = next_valid < v ? next_valid : v; }

    const bool roi    = (h >= ROI_V0) && (h <= ROI_V1) && (w >= ROI_U0) && (w <= ROI_U1);
    const bool accept = (!valid) && roi;    // == refine_mask == loss mask
    const int a  = prev_valid + 1;          // window start (invalid pixels)
    const int bb = next_valid - 1;          // window end

    // ---------------- Phase 4: refined argmax teacher ----------------
    float best  = -INFINITY;
    int   bestd = 0;
    #pragma unroll
    for (int d = 0; d < NDISP; ++d) {
        __syncthreads();                    // Pbuf/wsum reuse fence
        float v = (d <= w) ? cost[d] : 0.f; // cv: zeros where infeasible
        float sx = v;
        #pragma unroll
        for (int off = 1; off < 64; off <<= 1) {
            float y = __shfl_up(sx, off, 64);
            sx = (lane >= off) ? (sx + y) : sx;
        }
        if (lane == 63) wsum[wave] = sx;
        __syncthreads();
        float pre = 0.f;
        for (int i = 0; i < wave; ++i) pre += wsum[i];
        Pbuf[w + 1] = sx + pre;
        if (w == 0) Pbuf[0] = 0.f;
        __syncthreads();
        if (accept) {
            float num = Pbuf[bb + 1] - Pbuf[a];
            int mx  = a > d ? a : d;
            int den = (bb >= d) ? (bb - mx + 1) : 0;
            float aggv = (den > 0) ? (num / (float)den) : -INFINITY;
            if (aggv > best) { best = aggv; bestd = d; }   // first-max semantics
        }
    }

    // ---------------- Phase 5: masked smooth-L1 + reduction ----------------
    float myL = 0.f, myC = 0.f;
    if (accept) {
        float s  = sdisp[(size_t)(b * HH + h) * WW + w];
        float ad = fabsf(s - (float)bestd);
        myL = (ad < 1.f) ? (0.5f * ad * ad) : (ad - 0.5f);
        myC = 1.f;
    }
    #pragma unroll
    for (int off = 32; off > 0; off >>= 1) {
        myL += __shfl_down(myL, off, 64);
        myC += __shfl_down(myC, off, 64);
    }
    __syncthreads();
    if (lane == 0) { wredL[wave] = myL; wredC[wave] = myC; }
    __syncthreads();
    if (w == 0) {
        float tL = 0.f, tC = 0.f;
        for (int i = 0; i < 9; ++i) { tL += wredL[i]; tC += wredC[i]; }
        atomicAdd(&acc[b * 2],     tL);
        atomicAdd(&acc[b * 2 + 1], tC);
    }
}

__global__ void roi_ent_sl1_finalize(const float* __restrict__ acc, float* __restrict__ out)
{
    if (threadIdx.x == 0 && blockIdx.x == 0) {
        float s = 0.f;
        for (int b = 0; b < BATCH; ++b) {
            float c = acc[b * 2 + 1];
            s += acc[b * 2] / fmaxf(c, 1.f);
        }
        out[0] = s * (1.0f / BATCH);
    }
}

extern "C" void kernel_launch(void* const* d_in, const int* in_sizes, int n_in,
                              void* d_out, int out_size, void* d_ws, size_t ws_size,
                              hipStream_t stream) {
    const float* FqL = (const float*)d_in[0];
    const float* FqR = (const float*)d_in[1];
    const float* sd  = (const float*)d_in[2];
    float* out = (float*)d_out;
    float* acc = (float*)d_ws;

    hipMemsetAsync(acc, 0, 2 * BATCH * sizeof(float), stream);
    roi_ent_sl1_row_kernel<<<BATCH * HH, WW, 0, stream>>>(FqL, FqR, sd, acc);
    roi_ent_sl1_finalize<<<1, 64, 0, stream>>>(acc, out);
}